// Round 7
// baseline (302.916 us; speedup 1.0000x reference)
//
#include <hip/hip_runtime.h>
#include <math.h>

// Problem constants (reference: B=4, T=2048, C=1024, H=16, d=64)
#define BB   4
#define TT   2048
#define CC   1024
#define HH   16
#define DD   64
#define MM   (BB*TT)     // 8192 rows
#define NQKV (3*CC)      // 3072
#define LCH  128         // attention chunk length
#define NCH  (TT/LCH)    // 16 chunks per (b,h)
#define EPSF 1e-6f

// LDS strides (in shorts) for attention kernels — padded to break bank aliasing
#define QKST 72          // Q/K tile row stride
#define PST  136         // P tile row stride
#define VTST 136         // V-transposed tile row stride

typedef __bf16 bf16x8 __attribute__((ext_vector_type(8)));
typedef float  floatx4 __attribute__((ext_vector_type(4)));

__device__ __forceinline__ unsigned short f2bf(float f) {
  union { float f; unsigned int u; } v; v.f = f;
  unsigned int r = v.u + 0x7fffu + ((v.u >> 16) & 1u); // RNE
  return (unsigned short)(r >> 16);
}
__device__ __forceinline__ float bf2f(unsigned short s) {
  union { unsigned int u; float f; } v; v.u = ((unsigned int)s) << 16;
  return v.f;
}
__device__ __forceinline__ float featmap(float v) {
  // elu(v)+1
  return v > 0.f ? v + 1.f : __expf(v);
}
// async global->LDS, 16B per lane; LDS dest = wave-uniform base + lane*16
__device__ __forceinline__ void gld_lds_b128(const unsigned short* g, unsigned short* l) {
  __builtin_amdgcn_global_load_lds(
      (const __attribute__((address_space(1))) unsigned int*)g,
      (__attribute__((address_space(3))) unsigned int*)l, 16, 0, 0);
}

// ---------------- prep: x->bf16 + both weight transposes, one kernel ----------------
__device__ __forceinline__ void transpose_cvt_body(const float* __restrict__ W,
                                                   unsigned short* __restrict__ out,
                                                   int R, int Cc, int bx32, int by32, int tid) {
  __shared__ float tile[32][33];
  int tx = tid & 31, ty = tid >> 5;  // 32 x 8
  int bx = bx32 * 32, by = by32 * 32;
  #pragma unroll
  for (int i = ty; i < 32; i += 8)
    tile[i][tx] = W[(size_t)(by + i) * Cc + bx + tx];
  __syncthreads();
  #pragma unroll
  for (int i = ty; i < 32; i += 8)
    out[(size_t)(bx + i) * R + by + tx] = f2bf(tile[tx][i]);
}

// grid: [0,8192) cvt_x | [8192,11264) W_attn transpose | [11264,12288) W_proj transpose
__global__ __launch_bounds__(256) void prep_kernel(
    const float* __restrict__ x, unsigned short* __restrict__ xb,
    const float* __restrict__ Wa, unsigned short* __restrict__ WaT,
    const float* __restrict__ Wp, unsigned short* __restrict__ WpT) {
  int blk = blockIdx.x, tid = threadIdx.x;
  if (blk < 8192) {
    int i = (blk * 256 + tid) * 4;
    float4 f = *(const float4*)(x + i);
    ushort4 o;
    o.x = f2bf(f.x); o.y = f2bf(f.y); o.z = f2bf(f.z); o.w = f2bf(f.w);
    *(ushort4*)(xb + i) = o;
  } else if (blk < 8192 + 3072) {
    int t = blk - 8192;                       // 96 x 32
    transpose_cvt_body(Wa, WaT, CC, NQKV, t % 96, t / 96, tid);
  } else {
    int t = blk - 11264;                      // 32 x 32
    transpose_cvt_body(Wp, WpT, CC, CC, t % 32, t / 32, tid);
  }
}

// ========== MFMA GEMM core: 128x128, BK=64, W via LDS, x DIRECT global->VGPR ========
// A_: M x K bf16 row-major (x), Bt_: N x K bf16 row-major (W^T).
// 256 threads = 4 waves; wave w: wm=(w>>1)*64 (m rows), wn=(w&1)*64 (n rows).
// TRANSPOSED compute (R6): MFMA A-operand = W rows (from LDS Bs), B-operand = x rows
// loaded DIRECTLY from global (16B per lane, no barrier dependency -> compiler can
// hoist across MFMAs; halves LDS traffic 96->48 KB/block-iter, gld queue 8->4/wave).
// C/D: row=(lq*4+r)=n (4 consecutive dd), col=lr=m -> packed epilogue stores.
// LDS rows 128B, 16B-chunks XOR-swizzled by (row&7): measured 0 conflicts.
#define GEMM_K_LOOP(A_, Bt_, K_)                                                 \
  __shared__ __align__(16) unsigned short Bs[128 * 64];                          \
  int tid = threadIdx.x;                                                         \
  int wave = tid >> 6, lane = tid & 63;                                          \
  int lr = lane & 15, lq = lane >> 4;                                            \
  int m0 = blockIdx.y * 128, n0 = blockIdx.x * 128;                              \
  int wm = (wave >> 1) * 64, wn = (wave & 1) * 64;                               \
  int lrow = lane >> 3;                 /* 0..7: row within 8-row chunk */       \
  int lk = (lane & 7) ^ lrow;           /* swizzled source k-chunk */            \
  int rbase = wave * 32;                                                         \
  const unsigned short* gB = Bt_ + (size_t)(n0 + rbase + lrow) * K_ + lk * 8;    \
  unsigned short* lB = Bs + rbase * 64;                                          \
  const unsigned short* gA = A_ + (size_t)(m0 + wm + lr) * K_ + lq * 8;          \
  floatx4 acc[4][4] = {};                                                        \
  for (int k0 = 0; k0 < K_; k0 += 64) {                                          \
    __syncthreads(); /* prior W-frag reads done before overwrite */              \
    _Pragma("unroll")                                                            \
    for (int g = 0; g < 4; g++)                                                  \
      gld_lds_b128(gB + k0 + (size_t)g * 8 * K_, lB + g * 512);                  \
    bf16x8 bm[2][4]; /* x-side frags, direct from global */                      \
    _Pragma("unroll")                                                            \
    for (int kk = 0; kk < 2; kk++)                                               \
      _Pragma("unroll")                                                          \
      for (int j = 0; j < 4; j++)                                                \
        bm[kk][j] = *(const bf16x8*)&gA[k0 + kk * 32 + (size_t)j * 16 * K_];     \
    __syncthreads(); /* W staged visible */                                      \
    _Pragma("unroll")                                                            \
    for (int kk = 0; kk < 2; kk++) {                                             \
      bf16x8 an[4];                                                              \
      _Pragma("unroll")                                                          \
      for (int i = 0; i < 4; i++)                                                \
        an[i] = *(const bf16x8*)&Bs[(wn + i * 16 + lr) * 64 + ((((kk << 2) + lq) ^ (lr & 7)) << 3)]; \
      _Pragma("unroll")                                                          \
      for (int i = 0; i < 4; i++)                                                \
        _Pragma("unroll")                                                        \
        for (int j = 0; j < 4; j++)                                              \
          acc[i][j] = __builtin_amdgcn_mfma_f32_16x16x32_bf16(an[i], bm[kk][j], acc[i][j], 0, 0, 0); \
    }                                                                            \
  }

// ---------------- GEMM 1: qkv = x @ W_attn + b, split + feature map ----------------
// Transposed C/D: lane holds n = n0+wn+i*16+lq*4+{0..3} (4 consecutive dd, same head,
// same q/k/v third), m(t) = m0+wm+j*16+lr.
__global__ __launch_bounds__(256) void gemm_qkv_kernel(
    const unsigned short* __restrict__ A, const unsigned short* __restrict__ Bt,
    const float* __restrict__ bias,
    unsigned short* __restrict__ qh, unsigned short* __restrict__ kh,
    unsigned short* __restrict__ vh) {
  GEMM_K_LOOP(A, Bt, CC)
  int which = n0 >> 10;  // 0=q,1=k,2=v — uniform over the whole block
  unsigned short* dst = (which == 0) ? qh : (which == 1) ? kh : vh;
  #pragma unroll
  for (int i = 0; i < 4; i++) {
    int n = n0 + wn + i * 16 + lq * 4;
    int h = (n & 1023) >> 6, dd = n & 63;
    float4 bi = *(const float4*)&bias[n];
    #pragma unroll
    for (int j = 0; j < 4; j++) {
      int m = m0 + wm + j * 16 + lr;
      int b = m >> 11, t = m & 2047;
      float v0 = acc[i][j][0] + bi.x, v1 = acc[i][j][1] + bi.y;
      float v2 = acc[i][j][2] + bi.z, v3 = acc[i][j][3] + bi.w;
      if (which < 2) { v0 = featmap(v0); v1 = featmap(v1); v2 = featmap(v2); v3 = featmap(v3); }
      ushort4 o; o.x = f2bf(v0); o.y = f2bf(v1); o.z = f2bf(v2); o.w = f2bf(v3);
      size_t idx = (((size_t)(b * HH + h)) * TT + t) * DD + dd;
      *(ushort4*)&dst[idx] = o;
    }
  }
}

// ---------------- GEMM 2: out = y @ W_proj + b_proj (fp32 out) ----------------
__global__ __launch_bounds__(256) void gemm_proj_kernel(
    const unsigned short* __restrict__ A, const unsigned short* __restrict__ Bt,
    const float* __restrict__ bias, float* __restrict__ out) {
  GEMM_K_LOOP(A, Bt, CC)
  #pragma unroll
  for (int i = 0; i < 4; i++) {
    int n = n0 + wn + i * 16 + lq * 4;
    float4 bi = *(const float4*)&bias[n];
    #pragma unroll
    for (int j = 0; j < 4; j++) {
      int m = m0 + wm + j * 16 + lr;
      float4 o;
      o.x = acc[i][j][0] + bi.x; o.y = acc[i][j][1] + bi.y;
      o.z = acc[i][j][2] + bi.z; o.w = acc[i][j][3] + bi.w;
      *(float4*)&out[(size_t)m * CC + n] = o;
    }
  }
}

// ---------------- Phase A: per-chunk KV state (MFMA) ----------------
// grid: B*H*NCH blocks, 256 threads.
// KVx[blk][80][64] fp32, stored TRANSPOSED: KVx[j][i] = (K_c^T V_ext)[i][j],
// where V_ext = [V | ones | 0...] so col 64 is ksum. Rows 65..79 are zero.
__global__ __launch_bounds__(256) void chunk_state_kernel(
    const unsigned short* __restrict__ kh, const unsigned short* __restrict__ vh,
    float* __restrict__ KVx) {
  __shared__ __align__(16) unsigned short Kt[64 * VTST];   // K^T: Kt[i][t]
  __shared__ __align__(16) unsigned short Vt[80 * VTST];   // V^T + ones/zero rows
  int blk = blockIdx.x;
  int bh = blk / NCH, c = blk % NCH;
  int tid = threadIdx.x;
  const unsigned short* kp = kh + ((size_t)bh * TT + c * LCH) * DD;
  const unsigned short* vp = vh + ((size_t)bh * TT + c * LCH) * DD;
  {
    int t = tid & 127;
    for (int j8 = (tid >> 7) * 8; j8 < DD; j8 += 16) {
      union { uint4 u; unsigned short s[8]; } wk, wv;
      wk.u = *(const uint4*)&kp[(size_t)t * DD + j8];
      wv.u = *(const uint4*)&vp[(size_t)t * DD + j8];
      #pragma unroll
      for (int jj = 0; jj < 8; jj++) {
        Kt[(j8 + jj) * VTST + t] = wk.s[jj];
        Vt[(j8 + jj) * VTST + t] = wv.s[jj];
      }
    }
  }
  for (int e = tid; e < 16 * 128; e += 256) {
    int rr = e >> 7, n = e & 127;
    Vt[(64 + rr) * VTST + n] = (rr == 0) ? (unsigned short)0x3F80 : (unsigned short)0;
  }
  __syncthreads();
  int wave = tid >> 6, lane = tid & 63;
  int lr = lane & 15, lq = lane >> 4;
  int i0 = wave * 16;             // wave's 16-row band of K^T (i dimension)
  floatx4 acc[5] = {};
  #pragma unroll
  for (int kk = 0; kk < 4; kk++) {
    bf16x8 a = *(const bf16x8*)&Kt[(i0 + lr) * VTST + kk * 32 + lq * 8];
    #pragma unroll
    for (int jt = 0; jt < 5; jt++) {
      bf16x8 b = *(const bf16x8*)&Vt[(jt * 16 + lr) * VTST + kk * 32 + lq * 8];
      acc[jt] = __builtin_amdgcn_mfma_f32_16x16x32_bf16(a, b, acc[jt], 0, 0, 0);
    }
  }
  // C/D: col(j) = lane&15, row(i) = i0 + lq*4 + r; store transposed [j][i]
  float* o = KVx + (size_t)blk * 5120;
  #pragma unroll
  for (int jt = 0; jt < 5; jt++)
    #pragma unroll
    for (int r = 0; r < 4; r++)
      o[(jt * 16 + lr) * 64 + i0 + lq * 4 + r] = acc[jt][r];
}

// ---------------- Phase B: exclusive prefix over chunks -> bf16 SP_ext ----------
// SPb[blk][80][64] bf16 = sum_{c'<c} KVx[bh][c'][.][.]  (same [j][i] layout).
// grid: B*H*5 blocks (one per (bh, 16-row j-band)), 256 threads, 4 elems each.
__global__ __launch_bounds__(256) void prefix_state_kernel(const float* __restrict__ KVx,
                                                           unsigned short* __restrict__ SPb) {
  int bh = blockIdx.x / 5, jb = blockIdx.x % 5;
  int e = jb * 1024 + threadIdx.x * 4;
  float run0 = 0.f, run1 = 0.f, run2 = 0.f, run3 = 0.f;
  for (int c = 0; c < NCH; c++) {
    size_t base = ((size_t)bh * NCH + c) * 5120 + e;
    float4 v = *(const float4*)&KVx[base];
    ushort4 o;
    o.x = f2bf(run0); o.y = f2bf(run1); o.z = f2bf(run2); o.w = f2bf(run3);
    *(ushort4*)&SPb[base] = o;
    run0 += v.x; run1 += v.y; run2 += v.z; run3 += v.w;
  }
}

// ---------------- Phase C: per-chunk attention output (MFMA) ----------------
__global__ __launch_bounds__(256) void chunk_attn_kernel(
    const unsigned short* __restrict__ qh, const unsigned short* __restrict__ kh,
    const unsigned short* __restrict__ vh, const unsigned short* __restrict__ SPb,
    unsigned short* __restrict__ yb) {
  // region A: Qs[128][72] + Ks[128][72] = 18432 shorts, reused as P[128][136] = 17408
  // region B: Vt[80][136] = 10880 shorts
  __shared__ __align__(16) unsigned short lds[128 * QKST * 2 + 80 * VTST];  // 58624 B
  unsigned short* Qs = lds;                       // [128][QKST]
  unsigned short* Ks = lds + 128 * QKST;          // [128][QKST]
  unsigned short* P  = lds;                       // [128][PST] (after Qs/Ks dead)
  unsigned short* Vt = lds + 128 * QKST * 2;      // [80][VTST]

  int blk = blockIdx.x;
  int bh = blk / NCH, c = blk % NCH;
  int b = bh / HH, h = bh % HH;
  int tid = threadIdx.x;
  const unsigned short* qp = qh + ((size_t)bh * TT + c * LCH) * DD;
  const unsigned short* kp = kh + ((size_t)bh * TT + c * LCH) * DD;
  const unsigned short* vp = vh + ((size_t)bh * TT + c * LCH) * DD;

  // stage Q, K (row-major, padded stride)
  for (int e = tid; e < 1024; e += 256) {
    int row = e >> 3, k8 = (e & 7) * 8;
    *(uint4*)&Qs[row * QKST + k8] = *(const uint4*)&qp[(size_t)row * DD + k8];
    *(uint4*)&Ks[row * QKST + k8] = *(const uint4*)&kp[(size_t)row * DD + k8];
  }
  // stage V transposed: Vt[j][t] = V[t][j]
  {
    int t = tid & 127;
    for (int j8 = (tid >> 7) * 8; j8 < DD; j8 += 16) {
      union { uint4 u; unsigned short s[8]; } w;
      w.u = *(const uint4*)&vp[(size_t)t * DD + j8];
      #pragma unroll
      for (int jj = 0; jj < 8; jj++) Vt[(j8 + jj) * VTST + t] = w.s[jj];
    }
  }
  // ones row (j=64) and zero rows (65..79)
  for (int e = tid; e < 16 * 128; e += 256) {
    int rr = e >> 7, n = e & 127;
    Vt[(64 + rr) * VTST + n] = (rr == 0) ? (unsigned short)0x3F80 : (unsigned short)0;
  }
  __syncthreads();

  int wave = tid >> 6, lane = tid & 63;
  int lr = lane & 15, lq = lane >> 4;
  int mbase = wave * 32;

  // Q A-frags for this wave's two 16-row tiles
  bf16x8 aq[2][2];
  #pragma unroll
  for (int i = 0; i < 2; i++)
    #pragma unroll
    for (int kk = 0; kk < 2; kk++)
      aq[i][kk] = *(const bf16x8*)&Qs[(mbase + i * 16 + lr) * QKST + kk * 32 + lq * 8];

  floatx4 acc[2][5] = {};
  // inter-chunk: acc += Q @ SP_ext (B-frags from global)
  const unsigned short* spb = SPb + (size_t)blk * (80 * 64);
  #pragma unroll
  for (int jt = 0; jt < 5; jt++)
    #pragma unroll
    for (int kk = 0; kk < 2; kk++) {
      bf16x8 bsp = *(const bf16x8*)&spb[(jt * 16 + lr) * 64 + kk * 32 + lq * 8];
      acc[0][jt] = __builtin_amdgcn_mfma_f32_16x16x32_bf16(aq[0][kk], bsp, acc[0][jt], 0, 0, 0);
      acc[1][jt] = __builtin_amdgcn_mfma_f32_16x16x32_bf16(aq[1][kk], bsp, acc[1][jt], 0, 0, 0);
    }
  // intra-chunk scores: S = Q @ K^T
  floatx4 sacc[2][8] = {};
  #pragma unroll
  for (int nt = 0; nt < 8; nt++)
    #pragma unroll
    for (int kk = 0; kk < 2; kk++) {
      bf16x8 bk = *(const bf16x8*)&Ks[(nt * 16 + lr) * QKST + kk * 32 + lq * 8];
      sacc[0][nt] = __builtin_amdgcn_mfma_f32_16x16x32_bf16(aq[0][kk], bk, sacc[0][nt], 0, 0, 0);
      sacc[1][nt] = __builtin_amdgcn_mfma_f32_16x16x32_bf16(aq[1][kk], bk, sacc[1][nt], 0, 0, 0);
    }
  __syncthreads();  // everyone done reading Qs/Ks before P overwrites them

  // causal mask + bf16 round, C-layout -> LDS (A-layout for the PV matmul)
  #pragma unroll
  for (int i = 0; i < 2; i++)
    #pragma unroll
    for (int nt = 0; nt < 8; nt++) {
      int col = nt * 16 + lr;
      #pragma unroll
      for (int r = 0; r < 4; r++) {
        int m = mbase + i * 16 + lq * 4 + r;
        float v = (col <= m) ? sacc[i][nt][r] : 0.f;
        P[m * PST + col] = f2bf(v);
      }
    }
  __syncthreads();

  // acc += P @ V_ext
  #pragma unroll
  for (int kk4 = 0; kk4 < 4; kk4++) {
    bf16x8 ap0 = *(const bf16x8*)&P[(mbase + lr) * PST + kk4 * 32 + lq * 8];
    bf16x8 ap1 = *(const bf16x8*)&P[(mbase + 16 + lr) * PST + kk4 * 32 + lq * 8];
    #pragma unroll
    for (int jt = 0; jt < 5; jt++) {
      bf16x8 bv = *(const bf16x8*)&Vt[(jt * 16 + lr) * VTST + kk4 * 32 + lq * 8];
      acc[0][jt] = __builtin_amdgcn_mfma_f32_16x16x32_bf16(ap0, bv, acc[0][jt], 0, 0, 0);
      acc[1][jt] = __builtin_amdgcn_mfma_f32_16x16x32_bf16(ap1, bv, acc[1][jt], 0, 0, 0);
    }
  }

  // epilogue: den lives in col 64 -> lane (lq,0); broadcast within the 16-lane group
  int srclane = lq << 4;
  #pragma unroll
  for (int i = 0; i < 2; i++) {
    #pragma unroll
    for (int r = 0; r < 4; r++) {
      float den = __shfl(acc[i][4][r], srclane, 64);
      float inv = 1.f / (den + EPSF);
      int tg = c * LCH + mbase + i * 16 + lq * 4 + r;
      size_t base = ((size_t)b * TT + tg) * CC + h * DD;
      #pragma unroll
      for (int jt = 0; jt < 4; jt++)
        yb[base + jt * 16 + lr] = f2bf(acc[i][jt][r] * inv);
    }
  }
}

// ---------------- host launch ----------------
extern "C" void kernel_launch(void* const* d_in, const int* in_sizes, int n_in,
                              void* d_out, int out_size, void* d_ws, size_t ws_size,
                              hipStream_t stream) {
  const float* x      = (const float*)d_in[0];
  const float* W_attn = (const float*)d_in[1];
  const float* b_attn = (const float*)d_in[2];
  const float* W_proj = (const float*)d_in[3];
  const float* b_proj = (const float*)d_in[4];
  float* out = (float*)d_out;

  char* ws = (char*)d_ws;
  size_t off = 0;
  auto alloc = [&](size_t bytes) -> char* {
    char* p = ws + off;
    off += (bytes + 255) & ~(size_t)255;
    return p;
  };
  unsigned short* xb  = (unsigned short*)alloc((size_t)MM * CC * 2);   // reused as yb
  unsigned short* WaT = (unsigned short*)alloc((size_t)NQKV * CC * 2);
  unsigned short* WpT = (unsigned short*)alloc((size_t)CC * CC * 2);
  unsigned short* qh  = (unsigned short*)alloc((size_t)MM * CC * 2);
  unsigned short* kh  = (unsigned short*)alloc((size_t)MM * CC * 2);
  unsigned short* vh  = (unsigned short*)alloc((size_t)MM * CC * 2);
  float* KVx = (float*)alloc((size_t)BB * HH * NCH * 80 * 64 * 4);
  unsigned short* SPb = (unsigned short*)alloc((size_t)BB * HH * NCH * 80 * 64 * 2);
  unsigned short* yb = xb;  // xb dead after gemm_qkv

  prep_kernel<<<12288, 256, 0, stream>>>(x, xb, W_attn, WaT, W_proj, WpT);
  gemm_qkv_kernel<<<dim3(NQKV / 128, MM / 128), 256, 0, stream>>>(xb, WaT, b_attn, qh, kh, vh);
  chunk_state_kernel<<<BB * HH * NCH, 256, 0, stream>>>(kh, vh, KVx);
  prefix_state_kernel<<<BB * HH * 5, 256, 0, stream>>>(KVx, SPb);
  chunk_attn_kernel<<<BB * HH * NCH, 256, 0, stream>>>(qh, kh, vh, SPb, yb);
  gemm_proj_kernel<<<dim3(CC / 128, MM / 128), 256, 0, stream>>>(yb, WpT, b_proj, out);
}

// Round 8
// 234.147 us; speedup vs baseline: 1.2937x; 1.2937x over previous
//
#include <hip/hip_runtime.h>
#include <math.h>

// Problem constants (reference: B=4, T=2048, C=1024, H=16, d=64)
#define BB   4
#define TT   2048
#define CC   1024
#define HH   16
#define DD   64
#define MM   (BB*TT)     // 8192 rows
#define NQKV (3*CC)      // 3072
#define LCH  128         // attention chunk length
#define NCH  (TT/LCH)    // 16 chunks per (b,h)
#define EPSF 1e-6f

// LDS strides (in shorts) for attention kernels — padded to break bank aliasing
#define QKST 72          // Q/K tile row stride
#define PST  136         // P tile row stride
#define VTST 136         // V-transposed tile row stride

typedef __bf16 bf16x8 __attribute__((ext_vector_type(8)));
typedef float  floatx4 __attribute__((ext_vector_type(4)));

__device__ __forceinline__ unsigned short f2bf(float f) {
  union { float f; unsigned int u; } v; v.f = f;
  unsigned int r = v.u + 0x7fffu + ((v.u >> 16) & 1u); // RNE
  return (unsigned short)(r >> 16);
}
__device__ __forceinline__ float bf2f(unsigned short s) {
  union { unsigned int u; float f; } v; v.u = ((unsigned int)s) << 16;
  return v.f;
}
__device__ __forceinline__ float featmap(float v) {
  // elu(v)+1
  return v > 0.f ? v + 1.f : __expf(v);
}
// async global->LDS, 16B per lane; LDS dest = wave-uniform base + lane*16
__device__ __forceinline__ void gld_lds_b128(const unsigned short* g, unsigned short* l) {
  __builtin_amdgcn_global_load_lds(
      (const __attribute__((address_space(1))) unsigned int*)g,
      (__attribute__((address_space(3))) unsigned int*)l, 16, 0, 0);
}

// ---------------- prep: x->bf16 + both weight transposes, one kernel ----------------
__device__ __forceinline__ void transpose_cvt_body(const float* __restrict__ W,
                                                   unsigned short* __restrict__ out,
                                                   int R, int Cc, int bx32, int by32, int tid) {
  __shared__ float tile[32][33];
  int tx = tid & 31, ty = tid >> 5;  // 32 x 8
  int bx = bx32 * 32, by = by32 * 32;
  #pragma unroll
  for (int i = ty; i < 32; i += 8)
    tile[i][tx] = W[(size_t)(by + i) * Cc + bx + tx];
  __syncthreads();
  #pragma unroll
  for (int i = ty; i < 32; i += 8)
    out[(size_t)(bx + i) * R + by + tx] = f2bf(tile[tx][i]);
}

// grid: [0,8192) cvt_x | [8192,11264) W_attn transpose | [11264,12288) W_proj transpose
__global__ __launch_bounds__(256) void prep_kernel(
    const float* __restrict__ x, unsigned short* __restrict__ xb,
    const float* __restrict__ Wa, unsigned short* __restrict__ WaT,
    const float* __restrict__ Wp, unsigned short* __restrict__ WpT) {
  int blk = blockIdx.x, tid = threadIdx.x;
  if (blk < 8192) {
    int i = (blk * 256 + tid) * 4;
    float4 f = *(const float4*)(x + i);
    ushort4 o;
    o.x = f2bf(f.x); o.y = f2bf(f.y); o.z = f2bf(f.z); o.w = f2bf(f.w);
    *(ushort4*)(xb + i) = o;
  } else if (blk < 8192 + 3072) {
    int t = blk - 8192;                       // 96 x 32
    transpose_cvt_body(Wa, WaT, CC, NQKV, t % 96, t / 96, tid);
  } else {
    int t = blk - 11264;                      // 32 x 32
    transpose_cvt_body(Wp, WpT, CC, CC, t % 32, t / 32, tid);
  }
}

// ============== MFMA GEMM core: 128x128 tile, BK=64 (R6 known-good shape) ==========
// A: M x K bf16 row-major (x), Bt: N x K bf16 row-major (W^T).
// 256 threads = 4 waves; wave w: wm=(w>>1)*64 (m rows), wn=(w&1)*64 (n rows).
// TRANSPOSED compute (R6): operand-A frags come from Bs (W/n-side), operand-B frags
// from As (x/m-side), so C/D has row=(lq*4+r)=n, col=lr=m(t) -> each lane's 4 regs
// are 4 CONSECUTIVE n (dd) values => 8B/16B packed epilogue stores, no LDS roundtrip.
// Staging: global_load_lds w=16, rows 128B, 16B-chunks XOR-swizzled by (row&7) —
// measured 0 bank conflicts. acc[i][j]: i = n-tile, j = m-tile.
// NOTE (R4/R5/R7 post-mortems): BK changes, 128x256 tiles, and direct global->VGPR
// operands all regressed — this 2-barrier shape at ~5 blocks/CU is the plateau.
#define GEMM_K_LOOP(A_, Bt_, K_)                                                 \
  __shared__ __align__(16) unsigned short As[128 * 64];                          \
  __shared__ __align__(16) unsigned short Bs[128 * 64];                          \
  int tid = threadIdx.x;                                                         \
  int wave = tid >> 6, lane = tid & 63;                                          \
  int lr = lane & 15, lq = lane >> 4;                                            \
  int m0 = blockIdx.y * 128, n0 = blockIdx.x * 128;                              \
  int wm = (wave >> 1) * 64, wn = (wave & 1) * 64;                               \
  int lrow = lane >> 3;                 /* 0..7: row within 8-row chunk */       \
  int lk = (lane & 7) ^ lrow;           /* swizzled source k-chunk */            \
  int rbase = wave * 32;                                                         \
  const unsigned short* gA = A_ + (size_t)(m0 + rbase + lrow) * K_ + lk * 8;     \
  const unsigned short* gB = Bt_ + (size_t)(n0 + rbase + lrow) * K_ + lk * 8;    \
  unsigned short* lA = As + rbase * 64;                                          \
  unsigned short* lB = Bs + rbase * 64;                                          \
  floatx4 acc[4][4] = {};                                                        \
  for (int k0 = 0; k0 < K_; k0 += 64) {                                          \
    __syncthreads(); /* prior frag reads done before overwrite */                \
    _Pragma("unroll")                                                            \
    for (int g = 0; g < 4; g++) {                                                \
      gld_lds_b128(gA + k0 + (size_t)g * 8 * K_, lA + g * 512);                  \
      gld_lds_b128(gB + k0 + (size_t)g * 8 * K_, lB + g * 512);                  \
    }                                                                            \
    __syncthreads(); /* staged data visible */                                   \
    _Pragma("unroll")                                                            \
    for (int kk = 0; kk < 2; kk++) {                                             \
      bf16x8 an[4], bm[4];                                                       \
      _Pragma("unroll")                                                          \
      for (int i = 0; i < 4; i++)                                                \
        an[i] = *(const bf16x8*)&Bs[(wn + i * 16 + lr) * 64 + ((((kk << 2) + lq) ^ (lr & 7)) << 3)]; \
      _Pragma("unroll")                                                          \
      for (int j = 0; j < 4; j++)                                                \
        bm[j] = *(const bf16x8*)&As[(wm + j * 16 + lr) * 64 + ((((kk << 2) + lq) ^ (lr & 7)) << 3)]; \
      _Pragma("unroll")                                                          \
      for (int i = 0; i < 4; i++)                                                \
        _Pragma("unroll")                                                        \
        for (int j = 0; j < 4; j++)                                              \
          acc[i][j] = __builtin_amdgcn_mfma_f32_16x16x32_bf16(an[i], bm[j], acc[i][j], 0, 0, 0); \
    }                                                                            \
  }

// ---------------- GEMM 1: qkv = x @ W_attn + b, split + feature map ----------------
// Transposed C/D: lane holds n = n0+wn+i*16+lq*4+{0..3} (4 consecutive dd, same head,
// same q/k/v third), m(t) = m0+wm+j*16+lr.
__global__ __launch_bounds__(256) void gemm_qkv_kernel(
    const unsigned short* __restrict__ A, const unsigned short* __restrict__ Bt,
    const float* __restrict__ bias,
    unsigned short* __restrict__ qh, unsigned short* __restrict__ kh,
    unsigned short* __restrict__ vh) {
  GEMM_K_LOOP(A, Bt, CC)
  int which = n0 >> 10;  // 0=q,1=k,2=v — uniform over the whole block
  unsigned short* dst = (which == 0) ? qh : (which == 1) ? kh : vh;
  #pragma unroll
  for (int i = 0; i < 4; i++) {
    int n = n0 + wn + i * 16 + lq * 4;
    int h = (n & 1023) >> 6, dd = n & 63;
    float4 bi = *(const float4*)&bias[n];
    #pragma unroll
    for (int j = 0; j < 4; j++) {
      int m = m0 + wm + j * 16 + lr;
      int b = m >> 11, t = m & 2047;
      float v0 = acc[i][j][0] + bi.x, v1 = acc[i][j][1] + bi.y;
      float v2 = acc[i][j][2] + bi.z, v3 = acc[i][j][3] + bi.w;
      if (which < 2) { v0 = featmap(v0); v1 = featmap(v1); v2 = featmap(v2); v3 = featmap(v3); }
      ushort4 o; o.x = f2bf(v0); o.y = f2bf(v1); o.z = f2bf(v2); o.w = f2bf(v3);
      size_t idx = (((size_t)(b * HH + h)) * TT + t) * DD + dd;
      *(ushort4*)&dst[idx] = o;
    }
  }
}

// ---------------- GEMM 2: out = y @ W_proj + b_proj (fp32 out) ----------------
__global__ __launch_bounds__(256) void gemm_proj_kernel(
    const unsigned short* __restrict__ A, const unsigned short* __restrict__ Bt,
    const float* __restrict__ bias, float* __restrict__ out) {
  GEMM_K_LOOP(A, Bt, CC)
  #pragma unroll
  for (int i = 0; i < 4; i++) {
    int n = n0 + wn + i * 16 + lq * 4;
    float4 bi = *(const float4*)&bias[n];
    #pragma unroll
    for (int j = 0; j < 4; j++) {
      int m = m0 + wm + j * 16 + lr;
      float4 o;
      o.x = acc[i][j][0] + bi.x; o.y = acc[i][j][1] + bi.y;
      o.z = acc[i][j][2] + bi.z; o.w = acc[i][j][3] + bi.w;
      *(float4*)&out[(size_t)m * CC + n] = o;
    }
  }
}

// ---------------- Phase A: per-chunk KV state (MFMA) ----------------
// grid: B*H*NCH blocks, 256 threads.
// KVx[blk][80][64] fp32, stored TRANSPOSED: KVx[j][i] = (K_c^T V_ext)[i][j],
// where V_ext = [V | ones | 0...] so col 64 is ksum. Rows 65..79 are zero.
__global__ __launch_bounds__(256) void chunk_state_kernel(
    const unsigned short* __restrict__ kh, const unsigned short* __restrict__ vh,
    float* __restrict__ KVx) {
  __shared__ __align__(16) unsigned short Kt[64 * VTST];   // K^T: Kt[i][t]
  __shared__ __align__(16) unsigned short Vt[80 * VTST];   // V^T + ones/zero rows
  int blk = blockIdx.x;
  int bh = blk / NCH, c = blk % NCH;
  int tid = threadIdx.x;
  const unsigned short* kp = kh + ((size_t)bh * TT + c * LCH) * DD;
  const unsigned short* vp = vh + ((size_t)bh * TT + c * LCH) * DD;
  {
    int t = tid & 127;
    for (int j8 = (tid >> 7) * 8; j8 < DD; j8 += 16) {
      union { uint4 u; unsigned short s[8]; } wk, wv;
      wk.u = *(const uint4*)&kp[(size_t)t * DD + j8];
      wv.u = *(const uint4*)&vp[(size_t)t * DD + j8];
      #pragma unroll
      for (int jj = 0; jj < 8; jj++) {
        Kt[(j8 + jj) * VTST + t] = wk.s[jj];
        Vt[(j8 + jj) * VTST + t] = wv.s[jj];
      }
    }
  }
  for (int e = tid; e < 16 * 128; e += 256) {
    int rr = e >> 7, n = e & 127;
    Vt[(64 + rr) * VTST + n] = (rr == 0) ? (unsigned short)0x3F80 : (unsigned short)0;
  }
  __syncthreads();
  int wave = tid >> 6, lane = tid & 63;
  int lr = lane & 15, lq = lane >> 4;
  int i0 = wave * 16;             // wave's 16-row band of K^T (i dimension)
  floatx4 acc[5] = {};
  #pragma unroll
  for (int kk = 0; kk < 4; kk++) {
    bf16x8 a = *(const bf16x8*)&Kt[(i0 + lr) * VTST + kk * 32 + lq * 8];
    #pragma unroll
    for (int jt = 0; jt < 5; jt++) {
      bf16x8 b = *(const bf16x8*)&Vt[(jt * 16 + lr) * VTST + kk * 32 + lq * 8];
      acc[jt] = __builtin_amdgcn_mfma_f32_16x16x32_bf16(a, b, acc[jt], 0, 0, 0);
    }
  }
  // C/D: col(j) = lane&15, row(i) = i0 + lq*4 + r; store transposed [j][i].
  // 4 regs are 4 consecutive i -> float4 store.
  float* o = KVx + (size_t)blk * 5120;
  #pragma unroll
  for (int jt = 0; jt < 5; jt++)
    *(float4*)&o[(jt * 16 + lr) * 64 + i0 + lq * 4] = *(float4*)&acc[jt];
}

// ---------------- Phase B: exclusive prefix over chunks -> bf16 SP_ext ----------
// SPb[blk][80][64] bf16 = sum_{c'<c} KVx[bh][c'][.][.]  (same [j][i] layout).
// grid: B*H*5 blocks (one per (bh, 16-row j-band)), 256 threads, 4 elems each.
__global__ __launch_bounds__(256) void prefix_state_kernel(const float* __restrict__ KVx,
                                                           unsigned short* __restrict__ SPb) {
  int bh = blockIdx.x / 5, jb = blockIdx.x % 5;
  int e = jb * 1024 + threadIdx.x * 4;
  float run0 = 0.f, run1 = 0.f, run2 = 0.f, run3 = 0.f;
  for (int c = 0; c < NCH; c++) {
    size_t base = ((size_t)bh * NCH + c) * 5120 + e;
    float4 v = *(const float4*)&KVx[base];
    ushort4 o;
    o.x = f2bf(run0); o.y = f2bf(run1); o.z = f2bf(run2); o.w = f2bf(run3);
    *(ushort4*)&SPb[base] = o;
    run0 += v.x; run1 += v.y; run2 += v.z; run3 += v.w;
  }
}

// ---------------- Phase C: per-chunk attention output (MFMA, transposed) ----------
// R8: QSP and PV matmuls computed TRANSPOSED (A<->B swapped) so D[j][t]:
// row=(lq*4+r)=j (4 consecutive channels), col=lr=t -> packed ushort4 stores.
// Fragment reads are byte-identical (SPb is [j][i], Vt is [j][t], P is [t][t'],
// Q rows serve as B-operand [n=t][k]). QK^T + mask + P round-trip unchanged.
__global__ __launch_bounds__(256) void chunk_attn_kernel(
    const unsigned short* __restrict__ qh, const unsigned short* __restrict__ kh,
    const unsigned short* __restrict__ vh, const unsigned short* __restrict__ SPb,
    unsigned short* __restrict__ yb) {
  // region A: Qs[128][72] + Ks[128][72] = 18432 shorts, reused as P[128][136] = 17408
  // region B: Vt[80][136] = 10880 shorts
  __shared__ __align__(16) unsigned short lds[128 * QKST * 2 + 80 * VTST];  // 58624 B
  unsigned short* Qs = lds;                       // [128][QKST]
  unsigned short* Ks = lds + 128 * QKST;          // [128][QKST]
  unsigned short* P  = lds;                       // [128][PST] (after Qs/Ks dead)
  unsigned short* Vt = lds + 128 * QKST * 2;      // [80][VTST]

  int blk = blockIdx.x;
  int bh = blk / NCH, c = blk % NCH;
  int b = bh / HH, h = bh % HH;
  int tid = threadIdx.x;
  const unsigned short* qp = qh + ((size_t)bh * TT + c * LCH) * DD;
  const unsigned short* kp = kh + ((size_t)bh * TT + c * LCH) * DD;
  const unsigned short* vp = vh + ((size_t)bh * TT + c * LCH) * DD;

  // stage Q, K (row-major, padded stride)
  for (int e = tid; e < 1024; e += 256) {
    int row = e >> 3, k8 = (e & 7) * 8;
    *(uint4*)&Qs[row * QKST + k8] = *(const uint4*)&qp[(size_t)row * DD + k8];
    *(uint4*)&Ks[row * QKST + k8] = *(const uint4*)&kp[(size_t)row * DD + k8];
  }
  // stage V transposed: Vt[j][t] = V[t][j]
  {
    int t = tid & 127;
    for (int j8 = (tid >> 7) * 8; j8 < DD; j8 += 16) {
      union { uint4 u; unsigned short s[8]; } w;
      w.u = *(const uint4*)&vp[(size_t)t * DD + j8];
      #pragma unroll
      for (int jj = 0; jj < 8; jj++) Vt[(j8 + jj) * VTST + t] = w.s[jj];
    }
  }
  // ones row (j=64) and zero rows (65..79)
  for (int e = tid; e < 16 * 128; e += 256) {
    int rr = e >> 7, n = e & 127;
    Vt[(64 + rr) * VTST + n] = (rr == 0) ? (unsigned short)0x3F80 : (unsigned short)0;
  }
  __syncthreads();

  int wave = tid >> 6, lane = tid & 63;
  int lr = lane & 15, lq = lane >> 4;
  int mbase = wave * 32;

  // Q frags for this wave's two 16-row t-tiles (A-op for QK, B-op for QSP)
  bf16x8 aq[2][2];
  #pragma unroll
  for (int i = 0; i < 2; i++)
    #pragma unroll
    for (int kk = 0; kk < 2; kk++)
      aq[i][kk] = *(const bf16x8*)&Qs[(mbase + i * 16 + lr) * QKST + kk * 32 + lq * 8];

  // accT[jt][it]: D[j][t], rows j = jt*16 + lq*4 + r, cols t = mbase + it*16 + lr
  floatx4 accT[5][2] = {};
  // inter-chunk (transposed): accT += SP_ext^T-matmul: A = SPb rows [j][i], B = Q rows [t][i]
  const unsigned short* spb = SPb + (size_t)blk * (80 * 64);
  #pragma unroll
  for (int jt = 0; jt < 5; jt++)
    #pragma unroll
    for (int kk = 0; kk < 2; kk++) {
      bf16x8 asp = *(const bf16x8*)&spb[(jt * 16 + lr) * 64 + kk * 32 + lq * 8];
      accT[jt][0] = __builtin_amdgcn_mfma_f32_16x16x32_bf16(asp, aq[0][kk], accT[jt][0], 0, 0, 0);
      accT[jt][1] = __builtin_amdgcn_mfma_f32_16x16x32_bf16(asp, aq[1][kk], accT[jt][1], 0, 0, 0);
    }
  // intra-chunk scores: S = Q @ K^T (unchanged orientation: row=t(q), col=t'(k))
  floatx4 sacc[2][8] = {};
  #pragma unroll
  for (int nt = 0; nt < 8; nt++)
    #pragma unroll
    for (int kk = 0; kk < 2; kk++) {
      bf16x8 bk = *(const bf16x8*)&Ks[(nt * 16 + lr) * QKST + kk * 32 + lq * 8];
      sacc[0][nt] = __builtin_amdgcn_mfma_f32_16x16x32_bf16(aq[0][kk], bk, sacc[0][nt], 0, 0, 0);
      sacc[1][nt] = __builtin_amdgcn_mfma_f32_16x16x32_bf16(aq[1][kk], bk, sacc[1][nt], 0, 0, 0);
    }
  __syncthreads();  // everyone done reading Qs/Ks before P overwrites them

  // causal mask + bf16 round, C-layout -> LDS P[t][t']
  #pragma unroll
  for (int i = 0; i < 2; i++)
    #pragma unroll
    for (int nt = 0; nt < 8; nt++) {
      int col = nt * 16 + lr;
      #pragma unroll
      for (int r = 0; r < 4; r++) {
        int m = mbase + i * 16 + lq * 4 + r;
        float v = (col <= m) ? sacc[i][nt][r] : 0.f;
        P[m * PST + col] = f2bf(v);
      }
    }
  __syncthreads();

  // accT += (P @ V_ext)^T: A = Vt rows [j][t'], B = P rows [t][t']
  #pragma unroll
  for (int kk4 = 0; kk4 < 4; kk4++) {
    bf16x8 bp0 = *(const bf16x8*)&P[(mbase + lr) * PST + kk4 * 32 + lq * 8];
    bf16x8 bp1 = *(const bf16x8*)&P[(mbase + 16 + lr) * PST + kk4 * 32 + lq * 8];
    #pragma unroll
    for (int jt = 0; jt < 5; jt++) {
      bf16x8 av = *(const bf16x8*)&Vt[(jt * 16 + lr) * VTST + kk4 * 32 + lq * 8];
      accT[jt][0] = __builtin_amdgcn_mfma_f32_16x16x32_bf16(av, bp0, accT[jt][0], 0, 0, 0);
      accT[jt][1] = __builtin_amdgcn_mfma_f32_16x16x32_bf16(av, bp1, accT[jt][1], 0, 0, 0);
    }
  }

  // epilogue: den = row 64 = accT[4][it] reg0 on lanes lq=0, col=t=lane&15.
  // Each lane's col is t = lr -> broadcast from lane lr. 4 regs = 4 consecutive
  // channels -> ushort4 stores (8 per lane vs 32 scalar pre-R8).
  #pragma unroll
  for (int it = 0; it < 2; it++) {
    float den = __shfl(accT[4][it][0], lr, 64);
    float inv = 1.f / (den + EPSF);
    int tg = c * LCH + mbase + it * 16 + lr;
    size_t base = ((size_t)b * TT + tg) * CC + h * DD;
    #pragma unroll
    for (int jt = 0; jt < 4; jt++) {
      ushort4 o;
      o.x = f2bf(accT[jt][it][0] * inv);
      o.y = f2bf(accT[jt][it][1] * inv);
      o.z = f2bf(accT[jt][it][2] * inv);
      o.w = f2bf(accT[jt][it][3] * inv);
      *(ushort4*)&yb[base + jt * 16 + lq * 4] = o;
    }
  }
}

// ---------------- host launch ----------------
extern "C" void kernel_launch(void* const* d_in, const int* in_sizes, int n_in,
                              void* d_out, int out_size, void* d_ws, size_t ws_size,
                              hipStream_t stream) {
  const float* x      = (const float*)d_in[0];
  const float* W_attn = (const float*)d_in[1];
  const float* b_attn = (const float*)d_in[2];
  const float* W_proj = (const float*)d_in[3];
  const float* b_proj = (const float*)d_in[4];
  float* out = (float*)d_out;

  char* ws = (char*)d_ws;
  size_t off = 0;
  auto alloc = [&](size_t bytes) -> char* {
    char* p = ws + off;
    off += (bytes + 255) & ~(size_t)255;
    return p;
  };
  unsigned short* xb  = (unsigned short*)alloc((size_t)MM * CC * 2);   // reused as yb
  unsigned short* WaT = (unsigned short*)alloc((size_t)NQKV * CC * 2);
  unsigned short* WpT = (unsigned short*)alloc((size_t)CC * CC * 2);
  unsigned short* qh  = (unsigned short*)alloc((size_t)MM * CC * 2);
  unsigned short* kh  = (unsigned short*)alloc((size_t)MM * CC * 2);
  unsigned short* vh  = (unsigned short*)alloc((size_t)MM * CC * 2);
  float* KVx = (float*)alloc((size_t)BB * HH * NCH * 80 * 64 * 4);
  unsigned short* SPb = (unsigned short*)alloc((size_t)BB * HH * NCH * 80 * 64 * 2);
  unsigned short* yb = xb;  // xb dead after gemm_qkv

  prep_kernel<<<12288, 256, 0, stream>>>(x, xb, W_attn, WaT, W_proj, WpT);
  gemm_qkv_kernel<<<dim3(NQKV / 128, MM / 128), 256, 0, stream>>>(xb, WaT, b_attn, qh, kh, vh);
  chunk_state_kernel<<<BB * HH * NCH, 256, 0, stream>>>(kh, vh, KVx);
  prefix_state_kernel<<<BB * HH * 5, 256, 0, stream>>>(KVx, SPb);
  chunk_attn_kernel<<<BB * HH * NCH, 256, 0, stream>>>(qh, kh, vh, SPb, yb);
  gemm_proj_kernel<<<dim3(CC / 128, MM / 128), 256, 0, stream>>>(yb, WpT, b_proj, out);
}